// Round 13
// baseline (242.219 us; speedup 1.0000x reference)
//
#include <hip/hip_runtime.h>
#include <stdint.h>

// GCN layer: out = prelu(W @ segsum(A_val * h[A_col] -> A_row) + b, act_a)
//            h   = prelu(Wr @ AX + br, g_a)
// spmm (R1/R7 kernel) AT its random-line fetch ceiling: ~79us, beyond-L2
// fetch pinned 2.0-2.25 TB/s across 4 structures (R10); h-miss ~165MB ==
// compulsory floor. Failures: R8 PER-EDGE global atomics (145us); R11
// threadfence scan (device fence = XCD L2 flush/block); R13 64-block
// scatter ALONE (+37us, no co-resident work); R16 NT stores (+27us,
// defeats L2 write-combining). WINS: R14 266.7, R15 250.2, R18 237.1
// (two dispatches: memset -> [range-reserve scatter || GEMM] -> [spmm];
// per-bucket reservation atomics are fine, per-edge are not).
// R19: EXACT-RESIDENT MIXED GRID: dispatch-1 grid = 512 blocks = 2/CU
// (1024 thr), zero block queuing:
//  - scatter 128 blocks (chunk 12500): per-(block,bucket) run 2->4 edges
//    (32B) halves write-allocate RFO; reservation atomics halve; the 384
//    co-resident GEMM blocks keep CUs busy (R13's failure mode avoided).
//  - GEMM 384 blocks grid-stride 782 tiles; Ws(=Wr) is tile-invariant ->
//    staged ONCE, no per-tile barriers; X loads pipeline vs prev MFMAs.
// spmm byte-identical to R18.

typedef _Float16 half8 __attribute__((ext_vector_type(8)));
typedef _Float16 half4 __attribute__((ext_vector_type(4)));
typedef _Float16 half2v __attribute__((ext_vector_type(2)));
typedef float floatx4 __attribute__((ext_vector_type(4)));

#define LDK 136        // GEMM LDS row stride in halfs: 128 + 8
#define SHIFT 5        // 32 rows per bucket
#define NBMAX 3200     // >= ceil(100000/32) = 3125
#define SCATB 128      // scatter blocks (R19: 256 -> 128, runs 16B -> 32B)
#define GEMMG 384      // GEMM blocks (grid-stride over 782 tiles)
#define CAP 1024       // bucket stride / LDS sort window (max bucket ~650)

// ------ fused scatter + GEMM1 (1024-thr blocks, grid = SCATB+GEMMG = 512) --
// blocks [0,SCATB): chunk-local LDS hist -> per-bucket global range-reserve
// (cnt pre-zeroed by hipMemsetAsync) -> LDS-cursor scatter, cached stores.
// blocks [SCATB,512): h = prelu(AX@Wr^T+br), 16 waves, grid-stride tiles;
// block SCATB also converts W fp32->f16 for spmm.
__global__ __launch_bounds__(1024, 4)
void scatter_gemm(const int* __restrict__ rows, const int* __restrict__ cols,
                  const float* __restrict__ vals, int* __restrict__ cnt,
                  uint2* __restrict__ edges, int E, int chunk, int NB, int gemmB,
                  const float* __restrict__ X, const float* __restrict__ Wr,
                  const float* __restrict__ bias, const float* __restrict__ alpha_p,
                  _Float16* __restrict__ out, int N,
                  const float* __restrict__ W, _Float16* __restrict__ W16)
{
    __shared__ _Float16 Ws[128 * LDK];   // 34.8KB; scatter aliases a prefix
    const int tid = threadIdx.x;

    if (blockIdx.x < SCATB) {
        // ---------------- scatter path ----------------
        int* lh = (int*)Ws;                      // [NBMAX] counts -> cursors
        const int blk = blockIdx.x;
        for (int i = tid; i < NB; i += 1024) lh[i] = 0;
        __syncthreads();
        const int s0 = blk * chunk, e0 = min(E, s0 + chunk);
        for (int i = s0 + tid; i < e0; i += 1024)
            atomicAdd(&lh[rows[i] >> SHIFT], 1);
        __syncthreads();
        for (int b = tid; b < NB; b += 1024) {   // range-reserve: 1 atomic/bucket
            int c = lh[b];
            lh[b] = c ? (b << 10) + atomicAdd(&cnt[b], c) : 0;
        }
        __syncthreads();
        for (int i = s0 + tid; i < e0; i += 1024) {
            int r = rows[i];
            int b = r >> SHIFT;
            uint2 ed;
            ed.x = (unsigned)cols[i] | ((unsigned)(r & 31) << 20);
            ed.y = __float_as_uint(vals[i]);
            int p = atomicAdd(&lh[b], 1);        // LDS cursor = absolute slot
            if (p < ((b + 1) << 10)) edges[p] = ed;   // overflow guard (+22sigma)
        }
        return;
    }

    // ---------------- GEMM path: grid-stride tiles, Ws staged once ---------
    const float alpha = *alpha_p;
    const int g    = blockIdx.x - SCATB;         // 0..GEMMG-1
    const int wave = tid >> 6;       // 0..15
    const int lane = tid & 63;
    const int l15  = lane & 15;
    const int quad = lane >> 4;
    const int mt   = wave >> 1;      // m-tile 0..7 (16 rows each)
    const int nh   = wave & 1;       // n-half 0..1 (64 cols each)

    if (g == 0) {                    // W fp32 -> f16 (consumed by spmm next dispatch)
#pragma unroll
        for (int j = 0; j < 16; ++j) W16[tid + j * 1024] = (_Float16)W[tid + j * 1024];
    }

#pragma unroll
    for (int i = 0; i < 4; ++i) {    // stage Wr once (tile-invariant)
        int c   = tid + i * 1024;
        int row = c >> 5;
        int coff = (c & 31) * 4;
        float4 f = *(const float4*)(Wr + row * 128 + coff);
        half4 hv = { (_Float16)f.x, (_Float16)f.y, (_Float16)f.z, (_Float16)f.w };
        *(half4*)(&Ws[row * LDK + coff]) = hv;
    }
    __syncthreads();

    for (int t = g; t < gemmB; t += GEMMG) {
        const int bm = t * 128;
        half8 a[4];
        {
            const int xrow = bm + mt * 16 + l15;
            const bool ok = xrow < N;
            const float* xp = X + (size_t)xrow * 128 + quad * 8;
#pragma unroll
            for (int k = 0; k < 4; ++k) {
                half8 hv = {};
                if (ok) {
                    float4 f0 = *(const float4*)(xp + k * 32);
                    float4 f1 = *(const float4*)(xp + k * 32 + 4);
                    hv[0] = (_Float16)f0.x; hv[1] = (_Float16)f0.y;
                    hv[2] = (_Float16)f0.z; hv[3] = (_Float16)f0.w;
                    hv[4] = (_Float16)f1.x; hv[5] = (_Float16)f1.y;
                    hv[6] = (_Float16)f1.z; hv[7] = (_Float16)f1.w;
                }
                a[k] = hv;
            }
        }

        floatx4 acc[4] = {};
#pragma unroll
        for (int k = 0; k < 4; ++k) {
#pragma unroll
            for (int n = 0; n < 4; ++n) {
                int nc = nh * 4 + n;
                half8 b = *(const half8*)(&Ws[(nc * 16 + l15) * LDK + k * 32 + quad * 8]);
                acc[n] = __builtin_amdgcn_mfma_f32_16x16x32_f16(a[k], b, acc[n], 0, 0, 0);
            }
        }

#pragma unroll
        for (int n = 0; n < 4; ++n) {
            int col = (nh * 4 + n) * 16 + l15;
            float bcol = bias[col];
#pragma unroll
            for (int r = 0; r < 4; ++r) {
                int row = bm + mt * 16 + quad * 4 + r;
                if (row < N) {
                    float v = acc[n][r] + bcol;
                    v = (v >= 0.f) ? v : alpha * v;
                    out[(size_t)row * 128 + col] = (_Float16)v;
                }
            }
        }
    }
}

// ------- SpMM + GEMM2 fused (R1's proven kernel): per-bucket in-LDS sort,
// register accum, MFMA epilogue. block = 256 thr = 4 waves; bucket = 32 rows;
// wave w accumulates rows [w*8, w*8+8), lane l = cols {2l, 2l+1}. Then temp
// tile -> LDS -> out[32x128] = prelu(T @ W16^T + bias), 16 MFMAs/wave.
// Bucket range = [b<<10, b<<10 + min(cnt[b], CAP)).
__global__ __launch_bounds__(256, 8)
void spmm_fused(const int* __restrict__ cnt, const uint2* __restrict__ edges,
                const _Float16* __restrict__ h, const _Float16* __restrict__ W16,
                const float* __restrict__ bias, const float* __restrict__ alpha_p,
                float* __restrict__ out, int N)
{
    __shared__ uint2 eS[CAP];
    __shared__ _Float16 T[32 * LDK];
    __shared__ int bins[32], startS[33];

    const int tid  = threadIdx.x;
    const int wave = tid >> 6;
    const int lane = tid & 63;
    const int b    = blockIdx.x;
    const int s0   = b << 10;
    const int e0   = s0 + min(cnt[b], CAP);

    float acc[8][2] = {};

    for (int base = s0; base < e0; base += CAP) {
        const int n = min(CAP, e0 - base);
        if (tid < 32) bins[tid] = 0;
        __syncthreads();
        uint2 q[4];
#pragma unroll
        for (int u = 0; u < 4; ++u) {
            int i = tid + u * 256;
            if (i < n) {
                q[u] = edges[base + i];
                atomicAdd(&bins[q[u].x >> 20], 1);
            }
        }
        __syncthreads();
        if (tid < 32) {                    // wave-parallel 32-bin inclusive scan
            int x = bins[tid];
#pragma unroll
            for (int off = 1; off < 32; off <<= 1) {
                int y = __shfl_up(x, off);
                if (tid >= off) x += y;
            }
            startS[tid + 1] = x;
            if (tid == 0) startS[0] = 0;
            bins[tid] = x - bins[tid];     // bins becomes running cursor (exclusive)
        }
        __syncthreads();
#pragma unroll
        for (int u = 0; u < 4; ++u) {
            int i = tid + u * 256;
            if (i < n) {
                int p = atomicAdd(&bins[q[u].x >> 20], 1);
                eS[p] = q[u];
            }
        }
        __syncthreads();

#pragma unroll
        for (int j = 0; j < 8; ++j) {
            int r  = wave * 8 + j;
            int rs = startS[r], re = startS[r + 1];
            float a0r = acc[j][0], a1r = acc[j][1];
            int i = rs;
            for (; i + 7 < re; i += 8) {   // deep unroll: 8 gathers in flight
                uint2 q0 = eS[i],     q1 = eS[i + 1], q2 = eS[i + 2], q3 = eS[i + 3];
                uint2 q4 = eS[i + 4], q5 = eS[i + 5], q6 = eS[i + 6], q7 = eS[i + 7];
                half2v v0 = *(const half2v*)(h + (size_t)(q0.x & 0xFFFFF) * 128 + lane * 2);
                half2v v1 = *(const half2v*)(h + (size_t)(q1.x & 0xFFFFF) * 128 + lane * 2);
                half2v v2 = *(const half2v*)(h + (size_t)(q2.x & 0xFFFFF) * 128 + lane * 2);
                half2v v3 = *(const half2v*)(h + (size_t)(q3.x & 0xFFFFF) * 128 + lane * 2);
                half2v v4 = *(const half2v*)(h + (size_t)(q4.x & 0xFFFFF) * 128 + lane * 2);
                half2v v5 = *(const half2v*)(h + (size_t)(q5.x & 0xFFFFF) * 128 + lane * 2);
                half2v v6 = *(const half2v*)(h + (size_t)(q6.x & 0xFFFFF) * 128 + lane * 2);
                half2v v7 = *(const half2v*)(h + (size_t)(q7.x & 0xFFFFF) * 128 + lane * 2);
                float w0 = __uint_as_float(q0.y), w1 = __uint_as_float(q1.y);
                float w2 = __uint_as_float(q2.y), w3 = __uint_as_float(q3.y);
                float w4 = __uint_as_float(q4.y), w5 = __uint_as_float(q5.y);
                float w6 = __uint_as_float(q6.y), w7 = __uint_as_float(q7.y);
                a0r += w0 * (float)v0[0]; a1r += w0 * (float)v0[1];
                a0r += w1 * (float)v1[0]; a1r += w1 * (float)v1[1];
                a0r += w2 * (float)v2[0]; a1r += w2 * (float)v2[1];
                a0r += w3 * (float)v3[0]; a1r += w3 * (float)v3[1];
                a0r += w4 * (float)v4[0]; a1r += w4 * (float)v4[1];
                a0r += w5 * (float)v5[0]; a1r += w5 * (float)v5[1];
                a0r += w6 * (float)v6[0]; a1r += w6 * (float)v6[1];
                a0r += w7 * (float)v7[0]; a1r += w7 * (float)v7[1];
            }
            for (; i + 1 < re; i += 2) {
                uint2 q0 = eS[i], q1 = eS[i + 1];
                half2v v0 = *(const half2v*)(h + (size_t)(q0.x & 0xFFFFF) * 128 + lane * 2);
                half2v v1 = *(const half2v*)(h + (size_t)(q1.x & 0xFFFFF) * 128 + lane * 2);
                float w0 = __uint_as_float(q0.y), w1 = __uint_as_float(q1.y);
                a0r += w0 * (float)v0[0]; a1r += w0 * (float)v0[1];
                a0r += w1 * (float)v1[0]; a1r += w1 * (float)v1[1];
            }
            if (i < re) {
                uint2 q0 = eS[i];
                half2v v0 = *(const half2v*)(h + (size_t)(q0.x & 0xFFFFF) * 128 + lane * 2);
                float w0 = __uint_as_float(q0.y);
                a0r += w0 * (float)v0[0]; a1r += w0 * (float)v0[1];
            }
            acc[j][0] = a0r; acc[j][1] = a1r;
        }
        __syncthreads();   // protect eS before next chunk
    }

    // temp tile -> LDS (f16), row stride LDK breaks MFMA-read conflicts
#pragma unroll
    for (int j = 0; j < 8; ++j) {
        half2v o = { (_Float16)acc[j][0], (_Float16)acc[j][1] };
        *(half2v*)(&T[(wave * 8 + j) * LDK + lane * 2]) = o;
    }
    __syncthreads();

    // GEMM2 epilogue: out[32x128] = prelu(T @ W16^T + bias)
    const float alpha = *alpha_p;
    const int l15  = lane & 15;
    const int quad = lane >> 4;
    floatx4 c[2][2] = {};   // m-tiles {0,16} x n-tiles {wave*2, wave*2+1}
#pragma unroll
    for (int k0 = 0; k0 < 128; k0 += 32) {
        half8 a0 = *(const half8*)(&T[(     l15) * LDK + k0 + quad * 8]);
        half8 a1 = *(const half8*)(&T[(16 + l15) * LDK + k0 + quad * 8]);
#pragma unroll
        for (int nt = 0; nt < 2; ++nt) {
            int nrow = (wave * 2 + nt) * 16 + l15;
            half8 bf = *(const half8*)(W16 + nrow * 128 + k0 + quad * 8);
            c[0][nt] = __builtin_amdgcn_mfma_f32_16x16x32_f16(a0, bf, c[0][nt], 0, 0, 0);
            c[1][nt] = __builtin_amdgcn_mfma_f32_16x16x32_f16(a1, bf, c[1][nt], 0, 0, 0);
        }
    }
    const int row0 = b << SHIFT;
#pragma unroll
    for (int mt = 0; mt < 2; ++mt) {
#pragma unroll
        for (int nt = 0; nt < 2; ++nt) {
            int col = (wave * 2 + nt) * 16 + l15;
            float bcol = bias[col];
#pragma unroll
            for (int r = 0; r < 4; ++r) {
                int row = row0 + mt * 16 + quad * 4 + r;
                if (row < N) {
                    float v = c[mt][nt][r] + bcol;
                    v = (v >= 0.f) ? v : alpha * v;
                    out[(size_t)row * 128 + col] = v;
                }
            }
        }
    }
}

// ---------------- launcher ----------------
static inline size_t align256(size_t x) { return (x + 255) & ~(size_t)255; }

extern "C" void kernel_launch(void* const* d_in, const int* in_sizes, int n_in,
                              void* d_out, int out_size, void* d_ws, size_t ws_size,
                              hipStream_t stream)
{
    const float* AX        = (const float*)d_in[0];
    const int*   A_row     = (const int*)  d_in[1];
    const int*   A_col     = (const int*)  d_in[2];
    const float* A_val     = (const float*)d_in[3];
    const float* Wr_w      = (const float*)d_in[4];
    const float* Wr_b      = (const float*)d_in[5];
    const float* W_w       = (const float*)d_in[6];
    const float* W_b       = (const float*)d_in[7];
    const float* g_alpha   = (const float*)d_in[8];
    const float* act_alpha = (const float*)d_in[9];

    const int N = in_sizes[0] / 128;
    const int E = in_sizes[1];
    const int NB = (N + 31) >> SHIFT;            // 3125
    const int chunk = (E + SCATB - 1) / SCATB;   // 12500

    char* ws = (char*)d_ws;
    size_t off = 0;
    _Float16* h     = (_Float16*)(ws + off); off += align256((size_t)N * 128 * 2);
    uint2*    edges = (uint2*)   (ws + off); off += align256((size_t)NB * CAP * 8);
    int*      cnt   = (int*)     (ws + off); off += align256((size_t)NB * 4);
    _Float16* W16   = (_Float16*)(ws + off); off += align256((size_t)128 * 128 * 2);
    (void)ws_size; (void)n_in; (void)out_size;

    const int gemmB = (N + 127) / 128;           // 782

    hipMemsetAsync(cnt, 0, (size_t)NB * 4, stream);
    scatter_gemm<<<SCATB + GEMMG, 1024, 0, stream>>>(A_row, A_col, A_val, cnt, edges,
                                                     E, chunk, NB, gemmB,
                                                     AX, Wr_w, Wr_b, g_alpha, h, N,
                                                     W_w, W16);
    spmm_fused<<<NB, 256, 0, stream>>>(cnt, edges, h, W16, W_b, act_alpha,
                                       (float*)d_out, N);
}